// Round 8
// baseline (260.365 us; speedup 1.0000x reference)
//
#include <hip/hip_runtime.h>

#define Bn 256
#define Tn 512
#define Cn 256
#define Kn 8

typedef __attribute__((ext_vector_type(4))) float f32x4;

// One block per timestep t. 512 threads = 8 waves, 4/SIMD, 2 blocks/CU.
// Register-lean: peak live window kept < 128 (spill-free at launch_bounds 4).
//
// LDS tile: fp8 e4m3, L2-normalized (fp32 norm), paired-K swizzle:
// logical 8B half-unit b=kk*4+q of row r -> physical 16B unit
// u=((q*4+kp)^(r&7)), 8B half kk&1 (kp=kk>>1). One ds_read_b128 at (q,kp)
// feeds the MFMAs for kk=2kp and kk=2kp+1.
__global__ __launch_bounds__(512, 4)
void tcon_k(const float* __restrict__ emb,
            const int* __restrict__ phon,
            const float* __restrict__ wts,
            float* __restrict__ out) {
    __shared__ __align__(16) unsigned char Esh[Bn * Bn];   // 64 KiB fp8
    __shared__ int   pcls[Bn];
    __shared__ float csum[Kn];
    __shared__ int   ccnt[Kn];

    const int t    = blockIdx.x;
    const int tid  = threadIdx.x;
    const int lane = tid & 63;
    const int wave = tid >> 6;

    if (tid < Kn) { csum[tid] = 0.0f; ccnt[tid] = 0; }
    if (tid < Bn) pcls[tid] = phon[tid * Tn + t];

    // ---- Phase 1: 32 lanes <-> one row (8 floats/lane). Half-wave 5-step
    // shuffle reduce -> fp32 norm, normalize, fp8 convert, swizzled write.
    {
        const int b     = lane & 31;
        const int qb    = b & 3;
        const int kkb   = b >> 2;
        const int ubase = (qb << 2) + (kkb >> 1);
        const int half8 = (kkb & 1) << 3;
        #pragma unroll 2
        for (int it = 0; it < 16; ++it) {
            const int row = wave * 2 + (lane >> 5) + it * 16;
            const float4* p = (const float4*)(emb + ((size_t)row * Tn + t) * Cn) + 2 * b;
            const float4 v0 = p[0];
            const float4 v1 = p[1];
            float ss = v0.x*v0.x + v0.y*v0.y + v0.z*v0.z + v0.w*v0.w
                     + v1.x*v1.x + v1.y*v1.y + v1.z*v1.z + v1.w*v1.w;
            #pragma unroll
            for (int m = 1; m <= 16; m <<= 1) ss += __shfl_xor(ss, m, 64);
            const float inv = rsqrtf(fmaxf(ss, 1e-24f));
            int lo = __builtin_amdgcn_cvt_pk_fp8_f32(v0.x * inv, v0.y * inv, 0, false);
            lo     = __builtin_amdgcn_cvt_pk_fp8_f32(v0.z * inv, v0.w * inv, lo, true);
            int hi = __builtin_amdgcn_cvt_pk_fp8_f32(v1.x * inv, v1.y * inv, 0, false);
            hi     = __builtin_amdgcn_cvt_pk_fp8_f32(v1.z * inv, v1.w * inv, hi, true);
            int2 pk; pk.x = lo; pk.y = hi;
            *(int2*)&Esh[row * 256 + ((ubase ^ (row & 7)) << 4) + half8] = pk;
        }
    }
    __syncthreads();

    // ---- Phase 2: Gram strips via fp8 MFMA + fused epilogue ----
    const int q   = lane >> 4;
    const int l15 = lane & 15;
    const int e3  = l15 & 7;
    const int i0  = wave * 32;

    float num_p[8], den_p[8];
    int   pi[8];
    #pragma unroll
    for (int e = 0; e < 8; ++e) {
        const int irow = i0 + (e >> 2) * 16 + q * 4 + (e & 3);
        num_p[e] = 0.0f; den_p[e] = 0.0f;
        pi[e]    = pcls[irow];
    }

    f32x4 acc[2][4];
    for (int s = 0; s < 4; ++s) {
        const int jb = s * 64;
        #pragma unroll
        for (int m = 0; m < 2; ++m)
            #pragma unroll
            for (int n = 0; n < 4; ++n)
                acc[m][n] = (f32x4){0.f, 0.f, 0.f, 0.f};

        #pragma unroll
        for (int kp = 0; kp < 4; ++kp) {
            const int sw = (((q << 2) + kp) ^ e3) << 4;
            const ulonglong2 a0 = *(const ulonglong2*)&Esh[(i0 + l15) * 256 + sw];
            const ulonglong2 a1 = *(const ulonglong2*)&Esh[(i0 + 16 + l15) * 256 + sw];
            #pragma unroll
            for (int nh = 0; nh < 2; ++nh) {   // B pairs: narrow reg window
                const ulonglong2 b0 =
                    *(const ulonglong2*)&Esh[(jb + nh * 32 + l15) * 256 + sw];
                const ulonglong2 b1 =
                    *(const ulonglong2*)&Esh[(jb + nh * 32 + 16 + l15) * 256 + sw];
                acc[0][nh*2]   = __builtin_amdgcn_mfma_f32_16x16x32_fp8_fp8(
                    (long)a0.x, (long)b0.x, acc[0][nh*2], 0, 0, 0);
                acc[0][nh*2]   = __builtin_amdgcn_mfma_f32_16x16x32_fp8_fp8(
                    (long)a0.y, (long)b0.y, acc[0][nh*2], 0, 0, 0);
                acc[1][nh*2]   = __builtin_amdgcn_mfma_f32_16x16x32_fp8_fp8(
                    (long)a1.x, (long)b0.x, acc[1][nh*2], 0, 0, 0);
                acc[1][nh*2]   = __builtin_amdgcn_mfma_f32_16x16x32_fp8_fp8(
                    (long)a1.y, (long)b0.y, acc[1][nh*2], 0, 0, 0);
                acc[0][nh*2+1] = __builtin_amdgcn_mfma_f32_16x16x32_fp8_fp8(
                    (long)a0.x, (long)b1.x, acc[0][nh*2+1], 0, 0, 0);
                acc[0][nh*2+1] = __builtin_amdgcn_mfma_f32_16x16x32_fp8_fp8(
                    (long)a0.y, (long)b1.y, acc[0][nh*2+1], 0, 0, 0);
                acc[1][nh*2+1] = __builtin_amdgcn_mfma_f32_16x16x32_fp8_fp8(
                    (long)a1.x, (long)b1.x, acc[1][nh*2+1], 0, 0, 0);
                acc[1][nh*2+1] = __builtin_amdgcn_mfma_f32_16x16x32_fp8_fp8(
                    (long)a1.y, (long)b1.y, acc[1][nh*2+1], 0, 0, 0);
            }
        }

        #pragma unroll
        for (int n = 0; n < 4; ++n) {
            const int j  = jb + n * 16 + l15;
            const int pj = pcls[j];
            #pragma unroll
            for (int m = 0; m < 2; ++m)
                #pragma unroll
                for (int r = 0; r < 4; ++r) {
                    const int e  = m * 4 + r;
                    const int ir = i0 + m * 16 + q * 4 + r;
                    const float ex = __expf(acc[m][n][r]);
                    const bool nd = (ir != j);
                    den_p[e] += nd ? ex : 0.0f;
                    num_p[e] += (nd && (pj == pi[e])) ? ex : 0.0f;
                }
        }
    }

    // ---- Tail: quad reduce -> per-sample loss -> class accumulators ----
    #pragma unroll
    for (int e = 0; e < 8; ++e) {
        float n = num_p[e], d = den_p[e];
        #pragma unroll
        for (int m = 1; m <= 8; m <<= 1) {
            n += __shfl_xor(n, m, 64);
            d += __shfl_xor(d, m, 64);
        }
        if (l15 == e) {
            const int irow = i0 + (e >> 2) * 16 + q * 4 + (e & 3);
            const float ps = __logf(d + 1e-6f) - __logf(n);
            const int  cls = pi[e];
            atomicAdd(&csum[cls], ps);
            atomicAdd(&ccnt[cls], 1);
        }
    }
    __syncthreads();

    if (tid == 0) {
        float accv = 0.0f; int np = 0;
        #pragma unroll
        for (int k = 0; k < Kn; ++k)
            if (ccnt[k] > 0) { accv += (csum[k] / (float)ccnt[k]) * wts[k]; ++np; }
        atomicAdd(out, (accv / (float)np) * (1.0f / (float)Tn));
    }
}

extern "C" void kernel_launch(void* const* d_in, const int* in_sizes, int n_in,
                              void* d_out, int out_size, void* d_ws, size_t ws_size,
                              hipStream_t stream) {
    const float* emb  = (const float*)d_in[0];
    const int*   phon = (const int*)d_in[1];
    const float* wts  = (const float*)d_in[2];
    float*       out  = (float*)d_out;

    hipMemsetAsync(out, 0, sizeof(float), stream);
    tcon_k<<<Tn, 512, 0, stream>>>(emb, phon, wts, out);
}